// Round 12
// baseline (1441.433 us; speedup 1.0000x reference)
//
#include <hip/hip_runtime.h>
#include <hip/hip_bf16.h>

#define LPOS 8192
#define HDIM 128
#define M_TOT 4096          // B*Cin
#define GROW  136           // gp row stride (h 0..127, col128 = rowsum, pad to 16B rows)
#define GELEMS (M_TOT * GROW)        // 557056
#define KSPLIT 32
#define KCHUNK (LPOS / KSPLIT)       // 256 k per block = 4 chunks of 64
#define CUNITS 1024                  // 16-B units per 64-k chunk
#define BUNITS (4 * CUNITS)          // 4096 units = 65536 B LDS

typedef float  f32x4 __attribute__((ext_vector_type(4)));
typedef short  s16x8 __attribute__((ext_vector_type(8)));
typedef unsigned int u32x4 __attribute__((ext_vector_type(4)));

__device__ __forceinline__ unsigned short bf16_rne(float f) {
    unsigned u = __builtin_bit_cast(unsigned, f);
    u += 0x7fffu + ((u >> 16) & 1u);
    return (unsigned short)(u >> 16);
}
__device__ __forceinline__ float bf16f(unsigned short v) {
    return __builtin_bit_cast(float, (unsigned)v << 16);
}

__device__ __forceinline__ s16x8 cvt8(f32x4 a, f32x4 b) {
    s16x8 r;
    r[0] = (short)bf16_rne(a[0]); r[1] = (short)bf16_rne(a[1]);
    r[2] = (short)bf16_rne(a[2]); r[3] = (short)bf16_rne(a[3]);
    r[4] = (short)bf16_rne(b[0]); r[5] = (short)bf16_rne(b[1]);
    r[6] = (short)bf16_rne(b[2]); r[7] = (short)bf16_rne(b[3]);
    return r;
}

__device__ __forceinline__ float sum8(f32x4 a, f32x4 b) {
    return ((a[0] + a[1]) + (a[2] + a[3])) + ((b[0] + b[1]) + (b[2] + b[3]));
}

// ================= k1 body (shared by real kernel and probe) =================
__device__ __forceinline__ void k1_body(
        const float* __restrict__ w1, const float* __restrict__ b1,
        const float* __restrict__ w2, const float* __restrict__ b2,
        unsigned short* __restrict__ h2T,
        float* w2sT, float (*h1s)[HDIM * 8]) {
    const int tid = threadIdx.x;
    const int s = tid >> 7;
    const int h = tid & 127;

    for (int idx = tid; idx < HDIM * HDIM; idx += 256)
        w2sT[(idx & 127) * 129 + (idx >> 7)] = w2[idx];

    const int l0 = blockIdx.x * 16 + s * 8;
    const float myw1 = w1[h], myb1 = b1[h];
    #pragma unroll
    for (int ls = 0; ls < 8; ++ls) {
        float rel = -1.0f + (2.0f / 8191.0f) * (float)(l0 + ls);
        h1s[s][h * 8 + ls] = __sinf(30.0f * (rel * myw1 + myb1));
    }
    __syncthreads();

    const float bb = b2[h];
    float acc[8];
    #pragma unroll
    for (int ls = 0; ls < 8; ++ls) acc[ls] = bb;

    for (int j = 0; j < HDIM; ++j) {
        float wv = w2sT[j * 129 + h];
        const f32x4* hp = (const f32x4*)&h1s[s][j * 8];
        f32x4 p0 = hp[0], p1 = hp[1];
        acc[0] += wv * p0[0]; acc[1] += wv * p0[1];
        acc[2] += wv * p0[2]; acc[3] += wv * p0[3];
        acc[4] += wv * p1[0]; acc[5] += wv * p1[1];
        acc[6] += wv * p1[2]; acc[7] += wv * p1[3];
    }

    u32x4 ov;
    #pragma unroll
    for (int q = 0; q < 4; ++q) {
        unsigned lo = bf16_rne(__sinf(30.0f * acc[2 * q]));
        unsigned hi = bf16_rne(__sinf(30.0f * acc[2 * q + 1]));
        ov[q] = lo | (hi << 16);
    }
    const size_t c = (size_t)(l0 >> 6);
    const int k8 = (l0 >> 3) & 7;
    *(u32x4*)(h2T + (c * CUNITS + (size_t)k8 * 128 + h) * 8) = ov;
}

__global__ __launch_bounds__(256) void k1_siren(
        const float* __restrict__ w1, const float* __restrict__ b1,
        const float* __restrict__ w2, const float* __restrict__ b2,
        unsigned short* __restrict__ h2T) {
    __shared__ float w2sT[HDIM * 129];
    __shared__ __align__(16) float h1s[2][HDIM * 8];
    k1_body(w1, b1, w2, b2, h2T, w2sT, h1s);
}

__global__ __launch_bounds__(256) void k1_probe(
        const float* __restrict__ w1, const float* __restrict__ b1,
        const float* __restrict__ w2, const float* __restrict__ b2,
        unsigned short* __restrict__ h2T, int rep) {
    __shared__ float w2sT[HDIM * 129];
    __shared__ __align__(16) float h1s[2][HDIM * 8];
    #pragma unroll 1
    for (int rp = 0; rp < rep; ++rp) {
        k1_body(w1, b1, w2, b2, h2T, w2sT, h1s);
        __syncthreads();
    }
}

// ---------------- Kernel 2: partial GEMM (R9 exact; measured 14.2 us) --------
__global__ __launch_bounds__(256, 2) void k2_gemm(
        const float* __restrict__ x, const unsigned short* __restrict__ h2T,
        unsigned short* __restrict__ gp) {
    __shared__ unsigned short lds[BUNITS * 8];     // 65536 B

    const int lane = threadIdx.x & 63;
    const int wv   = threadIdx.x >> 6;
    const int r    = lane & 15;
    const int kg   = lane >> 4;
    const int m0   = blockIdx.x * 128;
    const int y    = blockIdx.y;
    const int kc   = y * KCHUNK;

    const float* xpa = x + (size_t)(m0 + wv * 32 + r) * LPOS + kc + kg * 8;
    const float* xpb = xpa + 16 * LPOS;

    f32x4 xr[2][2][4];

#define LOADX(SL, IT) do { \
        xr[SL][0][0] = *(const f32x4*)(xpa + (IT) * 64);      \
        xr[SL][0][1] = *(const f32x4*)(xpa + (IT) * 64 + 4);  \
        xr[SL][0][2] = *(const f32x4*)(xpa + (IT) * 64 + 32); \
        xr[SL][0][3] = *(const f32x4*)(xpa + (IT) * 64 + 36); \
        xr[SL][1][0] = *(const f32x4*)(xpb + (IT) * 64);      \
        xr[SL][1][1] = *(const f32x4*)(xpb + (IT) * 64 + 4);  \
        xr[SL][1][2] = *(const f32x4*)(xpb + (IT) * 64 + 32); \
        xr[SL][1][3] = *(const f32x4*)(xpb + (IT) * 64 + 36); \
    } while (0)

    {
        const unsigned short* src = h2T + (size_t)y * (BUNITS * 8);
        #pragma unroll
        for (int j = 0; j < 16; ++j) {
            const int U = j * 256 + threadIdx.x;
            __builtin_amdgcn_global_load_lds(
                (const unsigned int*)(src + (size_t)U * 8),
                (unsigned int*)&lds[U * 8], 16, 0, 0);
        }
    }
    LOADX(0, 0); LOADX(1, 1);

    f32x4 acc[2][8];
    #pragma unroll
    for (int s = 0; s < 2; ++s)
        #pragma unroll
        for (int t = 0; t < 8; ++t) { f32x4 z = {0.f,0.f,0.f,0.f}; acc[s][t] = z; }
    float sacc0 = 0.f, sacc1 = 0.f;

    __syncthreads();

    #pragma unroll
    for (int it = 0; it < 4; ++it) {
        const int sl = it & 1;
        s16x8 a0lo = cvt8(xr[sl][0][0], xr[sl][0][1]);
        s16x8 a0hi = cvt8(xr[sl][0][2], xr[sl][0][3]);
        s16x8 a1lo = cvt8(xr[sl][1][0], xr[sl][1][1]);
        s16x8 a1hi = cvt8(xr[sl][1][2], xr[sl][1][3]);
        sacc0 += sum8(xr[sl][0][0], xr[sl][0][1]) + sum8(xr[sl][0][2], xr[sl][0][3]);
        sacc1 += sum8(xr[sl][1][0], xr[sl][1][1]) + sum8(xr[sl][1][2], xr[sl][1][3]);
        if (it + 2 < 4) LOADX(sl, it + 2);

        #pragma unroll
        for (int t = 0; t < 8; ++t) {
            s16x8 blo = *(const s16x8*)&lds[((size_t)it * CUNITS + kg * 128 + t * 16 + r) * 8];
            s16x8 bhi = *(const s16x8*)&lds[((size_t)it * CUNITS + (kg + 4) * 128 + t * 16 + r) * 8];
            acc[0][t] = __builtin_amdgcn_mfma_f32_16x16x32_bf16(a0lo, blo, acc[0][t], 0, 0, 0);
            acc[0][t] = __builtin_amdgcn_mfma_f32_16x16x32_bf16(a0hi, bhi, acc[0][t], 0, 0, 0);
            acc[1][t] = __builtin_amdgcn_mfma_f32_16x16x32_bf16(a1lo, blo, acc[1][t], 0, 0, 0);
            acc[1][t] = __builtin_amdgcn_mfma_f32_16x16x32_bf16(a1hi, bhi, acc[1][t], 0, 0, 0);
        }
    }
#undef LOADX

    unsigned short* gpy = gp + (size_t)y * GELEMS;
    #pragma unroll
    for (int s = 0; s < 2; ++s) {
        #pragma unroll
        for (int t = 0; t < 8; ++t) {
            const int col = t * 16 + r;
            #pragma unroll
            for (int q = 0; q < 4; ++q) {
                const int row = m0 + wv * 32 + s * 16 + kg * 4 + q;
                gpy[(size_t)row * GROW + col] = bf16_rne(acc[s][t][q]);
            }
        }
    }
    sacc0 += __shfl_xor(sacc0, 16); sacc0 += __shfl_xor(sacc0, 32);
    sacc1 += __shfl_xor(sacc1, 16); sacc1 += __shfl_xor(sacc1, 32);
    if (kg == 0) {
        gpy[(size_t)(m0 + wv * 32 + r) * GROW + 128]      = bf16_rne(sacc0);
        gpy[(size_t)(m0 + wv * 32 + 16 + r) * GROW + 128] = bf16_rne(sacc1);
    }
}

// ================= k3 body (shared by real kernel and probe) =================
__device__ __forceinline__ void k3_body(
        const unsigned short* __restrict__ gp, const float* __restrict__ w3,
        const float* __restrict__ b3, float* __restrict__ part,
        unsigned short (*As)[64 * 128], unsigned short* Bs,
        float* b3s, float* sls) {
    const int bid = blockIdx.x;
    const int i   = bid >> 2;
    const int y0  = (bid & 3) * 8;
    const int t    = threadIdx.x;
    const int lane = t & 63;
    const int w    = t >> 6;
    const int r    = lane & 15;
    const int kg   = lane >> 4;

    #pragma unroll
    for (int p = 0; p < 4; ++p) {
        const int row  = p * 16 + (t >> 4);
        const int gran = t & 15;
        const float* src = w3 + (size_t)(row * 64 + i) * HDIM + gran * 8;
        f32x4 v0 = *(const f32x4*)src;
        f32x4 v1 = *(const f32x4*)(src + 4);
        *(s16x8*)&Bs[row * 128 + ((gran ^ (row & 7)) * 8)] = cvt8(v0, v1);
    }
    if (t < 64) b3s[t] = b3[t * 64 + i];

    float sreg = 0.f;
    auto stageA = [&](int y, int d) {
        const unsigned short* src = gp + (size_t)y * GELEMS + (size_t)i * GROW;
        #pragma unroll
        for (int p = 0; p < 4; ++p) {
            const int b    = p * 16 + (t >> 4);
            const int gran = t & 15;
            s16x8 v = *(const s16x8*)(src + (size_t)b * (64 * GROW) + gran * 8);
            *(s16x8*)&As[d][b * 128 + ((gran ^ (b & 7)) * 8)] = v;
        }
        if (t < 64) sreg += bf16f(src[(size_t)t * (64 * GROW) + 128]);
    };

    stageA(y0, 0);
    __syncthreads();

    s16x8 bfr[4][4];
    #pragma unroll
    for (int ct = 0; ct < 4; ++ct) {
        const int o = ct * 16 + r;
        #pragma unroll
        for (int ks = 0; ks < 4; ++ks)
            bfr[ct][ks] = *(const s16x8*)&Bs[o * 128 + (((ks * 4 + kg) ^ (o & 7)) * 8)];
    }

    f32x4 acc[4];
    #pragma unroll
    for (int ct = 0; ct < 4; ++ct) { f32x4 z = {0.f,0.f,0.f,0.f}; acc[ct] = z; }

    const int bA = w * 16 + r;
    #pragma unroll
    for (int yy = 0; yy < 8; ++yy) {
        if (yy + 1 < 8) stageA(y0 + yy + 1, (yy + 1) & 1);
        const unsigned short* buf = &As[yy & 1][0];
        s16x8 af[4];
        #pragma unroll
        for (int ks = 0; ks < 4; ++ks)
            af[ks] = *(const s16x8*)&buf[bA * 128 + (((ks * 4 + kg) ^ (bA & 7)) * 8)];
        #pragma unroll
        for (int ct = 0; ct < 4; ++ct)
            #pragma unroll
            for (int ks = 0; ks < 4; ++ks)
                acc[ct] = __builtin_amdgcn_mfma_f32_16x16x32_bf16(af[ks], bfr[ct][ks], acc[ct], 0, 0, 0);
        __syncthreads();
    }

    if (t < 64) sls[t] = sreg;
    __syncthreads();

    float* po = part + (size_t)bid * 4096;
    #pragma unroll
    for (int ct = 0; ct < 4; ++ct) {
        const int o = ct * 16 + r;
        #pragma unroll
        for (int q = 0; q < 4; ++q) {
            const int b = w * 16 + kg * 4 + q;
            po[b * 64 + o] = acc[ct][q] + sls[b] * b3s[o];
        }
    }
}

__global__ __launch_bounds__(256, 3) void k3_mm(
        const unsigned short* __restrict__ gp, const float* __restrict__ w3,
        const float* __restrict__ b3, float* __restrict__ part) {
    __shared__ unsigned short As[2][64 * 128];
    __shared__ unsigned short Bs[64 * 128];
    __shared__ float b3s[64];
    __shared__ float sls[64];
    k3_body(gp, w3, b3, part, As, Bs, b3s, sls);
}

__global__ __launch_bounds__(256, 3) void k3_probe(
        const unsigned short* __restrict__ gp, const float* __restrict__ w3,
        const float* __restrict__ b3, float* __restrict__ part, int rep) {
    __shared__ unsigned short As[2][64 * 128];
    __shared__ unsigned short Bs[64 * 128];
    __shared__ float b3s[64];
    __shared__ float sls[64];
    #pragma unroll 1
    for (int rp = 0; rp < rep; ++rp) {
        k3_body(gp, w3, b3, part, As, Bs, b3s, sls);
        __syncthreads();
    }
}

// ================= k4 (real + probe) =========================================
__global__ __launch_bounds__(256) void k4_final(
        const float* __restrict__ part, const float* __restrict__ bias,
        float* __restrict__ out) {
    const int idx = blockIdx.x * 256 + threadIdx.x;
    float s = bias[idx & 63];
    #pragma unroll 8
    for (int p = 0; p < 256; ++p)
        s += part[(size_t)p * 4096 + idx];
    out[idx] = s;
}

__global__ __launch_bounds__(256) void k4_probe(
        const float* __restrict__ part, const float* __restrict__ bias,
        float* __restrict__ out, int rep) {
    const int idx = blockIdx.x * 256 + threadIdx.x;
    #pragma unroll 1
    for (int rp = 0; rp < rep; ++rp) {
        float s = bias[idx & 63];
        #pragma unroll 8
        for (int p = 0; p < 256; ++p)
            s += part[(size_t)p * 4096 + idx];
        out[idx] = s;
    }
}

extern "C" void kernel_launch(void* const* d_in, const int* in_sizes, int n_in,
                              void* d_out, int out_size, void* d_ws, size_t ws_size,
                              hipStream_t stream) {
    (void)in_sizes; (void)n_in; (void)out_size; (void)ws_size;
    const float* x    = (const float*)d_in[0];
    const float* w1   = (const float*)d_in[1];
    const float* b1   = (const float*)d_in[2];
    const float* w2   = (const float*)d_in[3];
    const float* b2   = (const float*)d_in[4];
    const float* w3   = (const float*)d_in[5];
    const float* b3   = (const float*)d_in[6];
    const float* bias = (const float*)d_in[7];
    float* out = (float*)d_out;

    char* ws = (char*)d_ws;
    unsigned short* h2T = (unsigned short*)ws;                          // 2.10 MB
    const size_t H2T_BYTES = (size_t)(LPOS / 64) * CUNITS * 16;
    unsigned short* gp = (unsigned short*)(ws + H2T_BYTES);             // 35.7 MB
    const size_t GP_BYTES = (size_t)KSPLIT * GELEMS * 2;
    float* part = (float*)(ws + H2T_BYTES + GP_BYTES);                  // 4 MB
    // probe scratch
    unsigned short* h2T_p = (unsigned short*)(ws + (size_t)64 * 1024 * 1024);
    float* part_p         = (float*)(ws + (size_t)70 * 1024 * 1024);
    float* out_p          = (float*)(ws + (size_t)78 * 1024 * 1024);

    // real pipeline (R9 best-known, unchanged)
    k1_siren<<<LPOS / 16, 256, 0, stream>>>(w1, b1, w2, b2, h2T);
    k2_gemm<<<dim3(M_TOT / 128, KSPLIT), 256, 0, stream>>>(x, h2T, gp);
    k3_mm<<<256, 256, 0, stream>>>(gp, w3, b3, part);
    k4_final<<<16, 256, 0, stream>>>(part, bias, out);

    // measurement probes (reps sized to exceed the ~86us fill dispatches)
    k1_probe<<<LPOS / 16, 256, 0, stream>>>(w1, b1, w2, b2, h2T_p, 60);
    k3_probe<<<256, 256, 0, stream>>>(gp, w3, b3, part_p, 24);
    k4_probe<<<16, 256, 0, stream>>>(part, bias, out_p, 80);
}

// Round 14
// 257.777 us; speedup vs baseline: 5.5918x; 5.5918x over previous
//
#include <hip/hip_runtime.h>
#include <hip/hip_bf16.h>

#define LPOS 8192
#define HDIM 128
#define M_TOT 4096          // B*Cin
#define GROW  136           // gp row stride
#define GELEMS (M_TOT * GROW)
#define KSPLIT 32
#define KCHUNK (LPOS / KSPLIT)       // 256 k per k2-unit
#define CUNITS 1024                  // 16-B units per 64-k chunk
#define BUNITS (4 * CUNITS)          // 65536 B LDS for B
#define NBLK 512
#define NPART 512

typedef float  f32x4 __attribute__((ext_vector_type(4)));
typedef short  s16x8 __attribute__((ext_vector_type(8)));
typedef unsigned int u32x4 __attribute__((ext_vector_type(4)));

__device__ __forceinline__ unsigned short bf16_rne(float f) {
    unsigned u = __builtin_bit_cast(unsigned, f);
    u += 0x7fffu + ((u >> 16) & 1u);
    return (unsigned short)(u >> 16);
}
__device__ __forceinline__ float bf16f(unsigned short v) {
    return __builtin_bit_cast(float, (unsigned)v << 16);
}

__device__ __forceinline__ s16x8 cvt8(f32x4 a, f32x4 b) {
    s16x8 r;
    r[0] = (short)bf16_rne(a[0]); r[1] = (short)bf16_rne(a[1]);
    r[2] = (short)bf16_rne(a[2]); r[3] = (short)bf16_rne(a[3]);
    r[4] = (short)bf16_rne(b[0]); r[5] = (short)bf16_rne(b[1]);
    r[6] = (short)bf16_rne(b[2]); r[7] = (short)bf16_rne(b[3]);
    return r;
}

__device__ __forceinline__ float sum8(f32x4 a, f32x4 b) {
    return ((a[0] + a[1]) + (a[2] + a[3])) + ((b[0] + b[1]) + (b[2] + b[3]));
}

// Manual grid barrier: device-scope atomic arrive + spin-acquire (the pattern
// cg::grid_group::sync lowers to). bar = {counter, flag}, zeroed per launch.
__device__ __forceinline__ void gsync(unsigned* bar) {
    __syncthreads();
    if (threadIdx.x == 0) {
        __threadfence();   // belt-and-braces release of this block's writes
        unsigned a = __hip_atomic_fetch_add(&bar[0], 1u, __ATOMIC_ACQ_REL,
                                            __HIP_MEMORY_SCOPE_AGENT);
        if (a == NBLK - 1) {
            __hip_atomic_store(&bar[1], 1u, __ATOMIC_RELEASE,
                               __HIP_MEMORY_SCOPE_AGENT);
        } else {
            while (!__hip_atomic_load(&bar[1], __ATOMIC_ACQUIRE,
                                      __HIP_MEMORY_SCOPE_AGENT)) {}
        }
    }
    __syncthreads();
}

// ================== mega kernel: 4 phases, manual grid barriers ==============
// 512 blocks x 256 thr, static 74240 B LDS -> exactly 2 blocks/CU (all co-resident).
__global__ __launch_bounds__(256, 2) void mega(
        const float* __restrict__ x,  const float* __restrict__ w1,
        const float* __restrict__ b1, const float* __restrict__ w2,
        const float* __restrict__ b2, const float* __restrict__ w3,
        const float* __restrict__ b3, const float* __restrict__ bias,
        unsigned short* __restrict__ h2T, unsigned short* __restrict__ gp,
        float* __restrict__ part, unsigned* __restrict__ bars,
        float* __restrict__ out) {
    __shared__ __align__(16) char smem[74240];
    const int bid  = blockIdx.x;
    const int t    = threadIdx.x;
    const int lane = t & 63;
    const int wv   = t >> 6;
    const int r    = lane & 15;
    const int kg   = lane >> 4;

    // ---------------- Phase 1: SIREN -> h2T (R9 k1 body, 512 blocks) --------
    {
        float* w2sT = (float*)smem;                                  // 66048 B
        float (*h1s)[HDIM * 8] = (float(*)[HDIM * 8])(smem + 66048); // 8192 B
        const int s = t >> 7;
        const int h = t & 127;

        for (int idx = t; idx < HDIM * HDIM; idx += 256)
            w2sT[(idx & 127) * 129 + (idx >> 7)] = w2[idx];

        const int l0 = bid * 16 + s * 8;
        const float myw1 = w1[h], myb1 = b1[h];
        #pragma unroll
        for (int ls = 0; ls < 8; ++ls) {
            float rel = -1.0f + (2.0f / 8191.0f) * (float)(l0 + ls);
            h1s[s][h * 8 + ls] = __sinf(30.0f * (rel * myw1 + myb1));
        }
        __syncthreads();

        const float bb = b2[h];
        float acc[8];
        #pragma unroll
        for (int ls = 0; ls < 8; ++ls) acc[ls] = bb;

        for (int j = 0; j < HDIM; ++j) {
            float wvv = w2sT[j * 129 + h];
            const f32x4* hp = (const f32x4*)&h1s[s][j * 8];
            f32x4 p0 = hp[0], p1 = hp[1];
            acc[0] += wvv * p0[0]; acc[1] += wvv * p0[1];
            acc[2] += wvv * p0[2]; acc[3] += wvv * p0[3];
            acc[4] += wvv * p1[0]; acc[5] += wvv * p1[1];
            acc[6] += wvv * p1[2]; acc[7] += wvv * p1[3];
        }

        u32x4 ov;
        #pragma unroll
        for (int q = 0; q < 4; ++q) {
            unsigned lo = bf16_rne(__sinf(30.0f * acc[2 * q]));
            unsigned hi = bf16_rne(__sinf(30.0f * acc[2 * q + 1]));
            ov[q] = lo | (hi << 16);
        }
        const size_t c = (size_t)(l0 >> 6);
        const int k8 = (l0 >> 3) & 7;
        *(u32x4*)(h2T + (c * CUNITS + (size_t)k8 * 128 + h) * 8) = ov;
    }
    gsync(bars + 0);

    // ---------------- Phase 2: split-K GEMM (2 m-tiles per block, B once) ---
    {
        unsigned short* lds = (unsigned short*)smem;     // 65536 B
        const int y  = bid >> 4;
        const int kc = y * KCHUNK;

        {
            const unsigned short* srcB = h2T + (size_t)y * (BUNITS * 8);
            #pragma unroll
            for (int j = 0; j < 16; ++j) {
                const int U = j * 256 + t;
                __builtin_amdgcn_global_load_lds(
                    (const unsigned int*)(srcB + (size_t)U * 8),
                    (unsigned int*)&lds[U * 8], 16, 0, 0);
            }
        }

        unsigned short* gpy = gp + (size_t)y * GELEMS;

        #pragma unroll 1
        for (int un = 0; un < 2; ++un) {
            const int m0 = (((bid << 1) | un) & 31) * 128;
            const float* xpa = x + (size_t)(m0 + wv * 32 + r) * LPOS + kc + kg * 8;
            const float* xpb = xpa + 16 * LPOS;

            f32x4 xr[2][2][4];
#define LOADX(SL, IT) do { \
        xr[SL][0][0] = *(const f32x4*)(xpa + (IT) * 64);      \
        xr[SL][0][1] = *(const f32x4*)(xpa + (IT) * 64 + 4);  \
        xr[SL][0][2] = *(const f32x4*)(xpa + (IT) * 64 + 32); \
        xr[SL][0][3] = *(const f32x4*)(xpa + (IT) * 64 + 36); \
        xr[SL][1][0] = *(const f32x4*)(xpb + (IT) * 64);      \
        xr[SL][1][1] = *(const f32x4*)(xpb + (IT) * 64 + 4);  \
        xr[SL][1][2] = *(const f32x4*)(xpb + (IT) * 64 + 32); \
        xr[SL][1][3] = *(const f32x4*)(xpb + (IT) * 64 + 36); \
    } while (0)
            LOADX(0, 0); LOADX(1, 1);

            f32x4 acc[2][8];
            #pragma unroll
            for (int s = 0; s < 2; ++s)
                #pragma unroll
                for (int t8 = 0; t8 < 8; ++t8) { f32x4 z = {0.f,0.f,0.f,0.f}; acc[s][t8] = z; }
            float sacc0 = 0.f, sacc1 = 0.f;

            if (un == 0) __syncthreads();    // B staged; same-y B reused for un==1

            #pragma unroll
            for (int it = 0; it < 4; ++it) {
                const int sl = it & 1;
                s16x8 a0lo = cvt8(xr[sl][0][0], xr[sl][0][1]);
                s16x8 a0hi = cvt8(xr[sl][0][2], xr[sl][0][3]);
                s16x8 a1lo = cvt8(xr[sl][1][0], xr[sl][1][1]);
                s16x8 a1hi = cvt8(xr[sl][1][2], xr[sl][1][3]);
                sacc0 += sum8(xr[sl][0][0], xr[sl][0][1]) + sum8(xr[sl][0][2], xr[sl][0][3]);
                sacc1 += sum8(xr[sl][1][0], xr[sl][1][1]) + sum8(xr[sl][1][2], xr[sl][1][3]);
                if (it + 2 < 4) LOADX(sl, it + 2);

                #pragma unroll
                for (int t8 = 0; t8 < 8; ++t8) {
                    s16x8 blo = *(const s16x8*)&lds[((size_t)it * CUNITS + kg * 128 + t8 * 16 + r) * 8];
                    s16x8 bhi = *(const s16x8*)&lds[((size_t)it * CUNITS + (kg + 4) * 128 + t8 * 16 + r) * 8];
                    acc[0][t8] = __builtin_amdgcn_mfma_f32_16x16x32_bf16(a0lo, blo, acc[0][t8], 0, 0, 0);
                    acc[0][t8] = __builtin_amdgcn_mfma_f32_16x16x32_bf16(a0hi, bhi, acc[0][t8], 0, 0, 0);
                    acc[1][t8] = __builtin_amdgcn_mfma_f32_16x16x32_bf16(a1lo, blo, acc[1][t8], 0, 0, 0);
                    acc[1][t8] = __builtin_amdgcn_mfma_f32_16x16x32_bf16(a1hi, bhi, acc[1][t8], 0, 0, 0);
                }
            }
#undef LOADX

            #pragma unroll
            for (int s = 0; s < 2; ++s) {
                #pragma unroll
                for (int t8 = 0; t8 < 8; ++t8) {
                    const int col = t8 * 16 + r;
                    #pragma unroll
                    for (int q = 0; q < 4; ++q) {
                        const int row = m0 + wv * 32 + s * 16 + kg * 4 + q;
                        gpy[(size_t)row * GROW + col] = bf16_rne(acc[s][t8][q]);
                    }
                }
            }
            sacc0 += __shfl_xor(sacc0, 16); sacc0 += __shfl_xor(sacc0, 32);
            sacc1 += __shfl_xor(sacc1, 16); sacc1 += __shfl_xor(sacc1, 32);
            if (kg == 0) {
                gpy[(size_t)(m0 + wv * 32 + r) * GROW + 128]      = bf16_rne(sacc0);
                gpy[(size_t)(m0 + wv * 32 + 16 + r) * GROW + 128] = bf16_rne(sacc1);
            }
        }
    }
    gsync(bars + 2);

    // ---------------- Phase 3: per-i contraction, 512 blocks (4 y each) -----
    {
        unsigned short (*As)[64 * 128] = (unsigned short(*)[64 * 128])smem;
        unsigned short* Bs = (unsigned short*)(smem + 32768);
        float* b3s = (float*)(smem + 49152);
        float* sls = (float*)(smem + 49408);

        const int i  = bid >> 3;
        const int y0 = (bid & 7) * 4;

        #pragma unroll
        for (int p = 0; p < 4; ++p) {
            const int row  = p * 16 + (t >> 4);
            const int gran = t & 15;
            const float* src = w3 + (size_t)(row * 64 + i) * HDIM + gran * 8;
            f32x4 v0 = *(const f32x4*)src;
            f32x4 v1 = *(const f32x4*)(src + 4);
            *(s16x8*)&Bs[row * 128 + ((gran ^ (row & 7)) * 8)] = cvt8(v0, v1);
        }
        if (t < 64) b3s[t] = b3[t * 64 + i];

        float sreg = 0.f;
        auto stageA = [&](int y, int d) {
            const unsigned short* src = gp + (size_t)y * GELEMS + (size_t)i * GROW;
            #pragma unroll
            for (int p = 0; p < 4; ++p) {
                const int b    = p * 16 + (t >> 4);
                const int gran = t & 15;
                s16x8 v = *(const s16x8*)(src + (size_t)b * (64 * GROW) + gran * 8);
                *(s16x8*)&As[d][b * 128 + ((gran ^ (b & 7)) * 8)] = v;
            }
            if (t < 64) sreg += bf16f(src[(size_t)t * (64 * GROW) + 128]);
        };

        stageA(y0, 0);
        __syncthreads();

        s16x8 bfr[4][4];
        #pragma unroll
        for (int ct = 0; ct < 4; ++ct) {
            const int o = ct * 16 + r;
            #pragma unroll
            for (int ks = 0; ks < 4; ++ks)
                bfr[ct][ks] = *(const s16x8*)&Bs[o * 128 + (((ks * 4 + kg) ^ (o & 7)) * 8)];
        }

        f32x4 acc[4];
        #pragma unroll
        for (int ct = 0; ct < 4; ++ct) { f32x4 z = {0.f,0.f,0.f,0.f}; acc[ct] = z; }

        const int bA = wv * 16 + r;
        #pragma unroll
        for (int yy = 0; yy < 4; ++yy) {
            if (yy + 1 < 4) stageA(y0 + yy + 1, (yy + 1) & 1);
            const unsigned short* buf = &As[yy & 1][0];
            s16x8 af[4];
            #pragma unroll
            for (int ks = 0; ks < 4; ++ks)
                af[ks] = *(const s16x8*)&buf[bA * 128 + (((ks * 4 + kg) ^ (bA & 7)) * 8)];
            #pragma unroll
            for (int ct = 0; ct < 4; ++ct)
                #pragma unroll
                for (int ks = 0; ks < 4; ++ks)
                    acc[ct] = __builtin_amdgcn_mfma_f32_16x16x32_bf16(af[ks], bfr[ct][ks], acc[ct], 0, 0, 0);
            __syncthreads();
        }

        if (t < 64) sls[t] = sreg;
        __syncthreads();

        float* po = part + (size_t)bid * 4096;
        #pragma unroll
        for (int ct = 0; ct < 4; ++ct) {
            const int o = ct * 16 + r;
            #pragma unroll
            for (int q = 0; q < 4; ++q) {
                const int b = wv * 16 + kg * 4 + q;
                po[b * 64 + o] = acc[ct][q] + sls[b] * b3s[o];
            }
        }
    }
    gsync(bars + 4);

    // ---------------- Phase 4: final reduction over 512 partials ------------
    if (bid < 16) {
        const int idx = bid * 256 + t;
        float s = bias[idx & 63];
        #pragma unroll 16
        for (int p = 0; p < NPART; ++p)
            s += part[(size_t)p * 4096 + idx];
        out[idx] = s;
    }
}

extern "C" void kernel_launch(void* const* d_in, const int* in_sizes, int n_in,
                              void* d_out, int out_size, void* d_ws, size_t ws_size,
                              hipStream_t stream) {
    (void)in_sizes; (void)n_in; (void)out_size; (void)ws_size;
    const float* x    = (const float*)d_in[0];
    const float* w1   = (const float*)d_in[1];
    const float* b1   = (const float*)d_in[2];
    const float* w2   = (const float*)d_in[3];
    const float* b2   = (const float*)d_in[4];
    const float* w3   = (const float*)d_in[5];
    const float* b3   = (const float*)d_in[6];
    const float* bias = (const float*)d_in[7];
    float* out = (float*)d_out;

    char* ws = (char*)d_ws;
    unsigned short* h2T = (unsigned short*)ws;                          // 2.10 MB
    const size_t H2T_BYTES = (size_t)(LPOS / 64) * CUNITS * 16;
    unsigned short* gp = (unsigned short*)(ws + H2T_BYTES);             // 35.7 MB
    const size_t GP_BYTES = (size_t)KSPLIT * GELEMS * 2;
    float* part = (float*)(ws + H2T_BYTES + GP_BYTES);                  // 8 MB
    unsigned* bars = (unsigned*)(ws + (size_t)200 * 1024 * 1024);       // 3x{cnt,flag}

    hipMemsetAsync(bars, 0, 6 * sizeof(unsigned), stream);

    void* args_unused = nullptr; (void)args_unused;
    mega<<<NBLK, 256, 0, stream>>>(x, w1, b1, w2, b2, w3, b3, bias,
                                   h2T, gp, part, bars, out);
}

// Round 15
// 75.883 us; speedup vs baseline: 18.9954x; 3.3970x over previous
//
#include <hip/hip_runtime.h>
#include <hip/hip_bf16.h>

#define LPOS 8192
#define HDIM 128
#define M_TOT 4096          // B*Cin
#define GROW  136           // gp row stride (h 0..127, col128 = rowsum, pad to 16B rows)
#define GELEMS (M_TOT * GROW)        // 557056
#define KSPLIT 32
#define KCHUNK (LPOS / KSPLIT)       // 256 k per block = 4 chunks of 64
#define CUNITS 1024                  // 16-B units per 64-k chunk
#define BUNITS (4 * CUNITS)          // 4096 units = 65536 B LDS
#define NPART 512

typedef float  f32x4 __attribute__((ext_vector_type(4)));
typedef short  s16x8 __attribute__((ext_vector_type(8)));
typedef unsigned int u32x4 __attribute__((ext_vector_type(4)));

__device__ __forceinline__ unsigned short bf16_rne(float f) {
    unsigned u = __builtin_bit_cast(unsigned, f);
    u += 0x7fffu + ((u >> 16) & 1u);
    return (unsigned short)(u >> 16);
}
__device__ __forceinline__ float bf16f(unsigned short v) {
    return __builtin_bit_cast(float, (unsigned)v << 16);
}

__device__ __forceinline__ s16x8 cvt8(f32x4 a, f32x4 b) {
    s16x8 r;
    r[0] = (short)bf16_rne(a[0]); r[1] = (short)bf16_rne(a[1]);
    r[2] = (short)bf16_rne(a[2]); r[3] = (short)bf16_rne(a[3]);
    r[4] = (short)bf16_rne(b[0]); r[5] = (short)bf16_rne(b[1]);
    r[6] = (short)bf16_rne(b[2]); r[7] = (short)bf16_rne(b[3]);
    return r;
}

__device__ __forceinline__ float sum8(f32x4 a, f32x4 b) {
    return ((a[0] + a[1]) + (a[2] + a[3])) + ((b[0] + b[1]) + (b[2] + b[3]));
}

// ---------------- Kernel 1: SIREN -> h2T (R9 exact) --------------------------
__global__ __launch_bounds__(256) void k1_siren(
        const float* __restrict__ w1, const float* __restrict__ b1,
        const float* __restrict__ w2, const float* __restrict__ b2,
        unsigned short* __restrict__ h2T) {
    __shared__ float w2sT[HDIM * 129];
    __shared__ __align__(16) float h1s[2][HDIM * 8];
    const int tid = threadIdx.x;
    const int s = tid >> 7;
    const int h = tid & 127;

    for (int idx = tid; idx < HDIM * HDIM; idx += 256)
        w2sT[(idx & 127) * 129 + (idx >> 7)] = w2[idx];

    const int l0 = blockIdx.x * 16 + s * 8;
    const float myw1 = w1[h], myb1 = b1[h];
    #pragma unroll
    for (int ls = 0; ls < 8; ++ls) {
        float rel = -1.0f + (2.0f / 8191.0f) * (float)(l0 + ls);
        h1s[s][h * 8 + ls] = __sinf(30.0f * (rel * myw1 + myb1));
    }
    __syncthreads();

    const float bb = b2[h];
    float acc[8];
    #pragma unroll
    for (int ls = 0; ls < 8; ++ls) acc[ls] = bb;

    for (int j = 0; j < HDIM; ++j) {
        float wv = w2sT[j * 129 + h];
        const f32x4* hp = (const f32x4*)&h1s[s][j * 8];
        f32x4 p0 = hp[0], p1 = hp[1];
        acc[0] += wv * p0[0]; acc[1] += wv * p0[1];
        acc[2] += wv * p0[2]; acc[3] += wv * p0[3];
        acc[4] += wv * p1[0]; acc[5] += wv * p1[1];
        acc[6] += wv * p1[2]; acc[7] += wv * p1[3];
    }

    u32x4 ov;
    #pragma unroll
    for (int q = 0; q < 4; ++q) {
        unsigned lo = bf16_rne(__sinf(30.0f * acc[2 * q]));
        unsigned hi = bf16_rne(__sinf(30.0f * acc[2 * q + 1]));
        ov[q] = lo | (hi << 16);
    }
    const size_t c = (size_t)(l0 >> 6);
    const int k8 = (l0 >> 3) & 7;
    *(u32x4*)(h2T + (c * CUNITS + (size_t)k8 * 128 + h) * 8) = ov;
}

// ---------------- Kernel 2: partial GEMM (R9 exact; measured 14.2 us) --------
__global__ __launch_bounds__(256, 2) void k2_gemm(
        const float* __restrict__ x, const unsigned short* __restrict__ h2T,
        unsigned short* __restrict__ gp) {
    __shared__ unsigned short lds[BUNITS * 8];     // 65536 B

    const int lane = threadIdx.x & 63;
    const int wv   = threadIdx.x >> 6;
    const int r    = lane & 15;
    const int kg   = lane >> 4;
    const int m0   = blockIdx.x * 128;
    const int y    = blockIdx.y;
    const int kc   = y * KCHUNK;

    const float* xpa = x + (size_t)(m0 + wv * 32 + r) * LPOS + kc + kg * 8;
    const float* xpb = xpa + 16 * LPOS;

    f32x4 xr[2][2][4];

#define LOADX(SL, IT) do { \
        xr[SL][0][0] = *(const f32x4*)(xpa + (IT) * 64);      \
        xr[SL][0][1] = *(const f32x4*)(xpa + (IT) * 64 + 4);  \
        xr[SL][0][2] = *(const f32x4*)(xpa + (IT) * 64 + 32); \
        xr[SL][0][3] = *(const f32x4*)(xpa + (IT) * 64 + 36); \
        xr[SL][1][0] = *(const f32x4*)(xpb + (IT) * 64);      \
        xr[SL][1][1] = *(const f32x4*)(xpb + (IT) * 64 + 4);  \
        xr[SL][1][2] = *(const f32x4*)(xpb + (IT) * 64 + 32); \
        xr[SL][1][3] = *(const f32x4*)(xpb + (IT) * 64 + 36); \
    } while (0)

    {
        const unsigned short* src = h2T + (size_t)y * (BUNITS * 8);
        #pragma unroll
        for (int j = 0; j < 16; ++j) {
            const int U = j * 256 + threadIdx.x;
            __builtin_amdgcn_global_load_lds(
                (const unsigned int*)(src + (size_t)U * 8),
                (unsigned int*)&lds[U * 8], 16, 0, 0);
        }
    }
    LOADX(0, 0); LOADX(1, 1);

    f32x4 acc[2][8];
    #pragma unroll
    for (int s = 0; s < 2; ++s)
        #pragma unroll
        for (int t = 0; t < 8; ++t) { f32x4 z = {0.f,0.f,0.f,0.f}; acc[s][t] = z; }
    float sacc0 = 0.f, sacc1 = 0.f;

    __syncthreads();

    #pragma unroll
    for (int it = 0; it < 4; ++it) {
        const int sl = it & 1;
        s16x8 a0lo = cvt8(xr[sl][0][0], xr[sl][0][1]);
        s16x8 a0hi = cvt8(xr[sl][0][2], xr[sl][0][3]);
        s16x8 a1lo = cvt8(xr[sl][1][0], xr[sl][1][1]);
        s16x8 a1hi = cvt8(xr[sl][1][2], xr[sl][1][3]);
        sacc0 += sum8(xr[sl][0][0], xr[sl][0][1]) + sum8(xr[sl][0][2], xr[sl][0][3]);
        sacc1 += sum8(xr[sl][1][0], xr[sl][1][1]) + sum8(xr[sl][1][2], xr[sl][1][3]);
        if (it + 2 < 4) LOADX(sl, it + 2);

        #pragma unroll
        for (int t = 0; t < 8; ++t) {
            s16x8 blo = *(const s16x8*)&lds[((size_t)it * CUNITS + kg * 128 + t * 16 + r) * 8];
            s16x8 bhi = *(const s16x8*)&lds[((size_t)it * CUNITS + (kg + 4) * 128 + t * 16 + r) * 8];
            acc[0][t] = __builtin_amdgcn_mfma_f32_16x16x32_bf16(a0lo, blo, acc[0][t], 0, 0, 0);
            acc[0][t] = __builtin_amdgcn_mfma_f32_16x16x32_bf16(a0hi, bhi, acc[0][t], 0, 0, 0);
            acc[1][t] = __builtin_amdgcn_mfma_f32_16x16x32_bf16(a1lo, blo, acc[1][t], 0, 0, 0);
            acc[1][t] = __builtin_amdgcn_mfma_f32_16x16x32_bf16(a1hi, bhi, acc[1][t], 0, 0, 0);
        }
    }
#undef LOADX

    unsigned short* gpy = gp + (size_t)y * GELEMS;
    #pragma unroll
    for (int s = 0; s < 2; ++s) {
        #pragma unroll
        for (int t = 0; t < 8; ++t) {
            const int col = t * 16 + r;
            #pragma unroll
            for (int q = 0; q < 4; ++q) {
                const int row = m0 + wv * 32 + s * 16 + kg * 4 + q;
                gpy[(size_t)row * GROW + col] = bf16_rne(acc[s][t][q]);
            }
        }
    }
    sacc0 += __shfl_xor(sacc0, 16); sacc0 += __shfl_xor(sacc0, 32);
    sacc1 += __shfl_xor(sacc1, 16); sacc1 += __shfl_xor(sacc1, 32);
    if (kg == 0) {
        gpy[(size_t)(m0 + wv * 32 + r) * GROW + 128]      = bf16_rne(sacc0);
        gpy[(size_t)(m0 + wv * 32 + 16 + r) * GROW + 128] = bf16_rne(sacc1);
    }
}

// ---------------- Kernel 3: per-i contraction, SPLIT to 512 blocks -----------
// bid = i*8 + yg; each block covers 4 y (serial chain halved vs R9's 8) and
// runs at 2 blocks/CU (512 blocks, 48.6 KB LDS) so stage latency cross-hides.
__global__ __launch_bounds__(256, 3) void k3_mm(
        const unsigned short* __restrict__ gp, const float* __restrict__ w3,
        const float* __restrict__ b3, float* __restrict__ part) {
    __shared__ unsigned short As[2][64 * 128];   // 2 x 16 KB
    __shared__ unsigned short Bs[64 * 128];      // 16 KB
    __shared__ float b3s[64];
    __shared__ float sls[64];

    const int bid = blockIdx.x;
    const int i   = bid >> 3;
    const int y0  = (bid & 7) * 4;
    const int t    = threadIdx.x;
    const int lane = t & 63;
    const int w    = t >> 6;
    const int r    = lane & 15;
    const int kg   = lane >> 4;

    #pragma unroll
    for (int p = 0; p < 4; ++p) {
        const int row  = p * 16 + (t >> 4);
        const int gran = t & 15;
        const float* src = w3 + (size_t)(row * 64 + i) * HDIM + gran * 8;
        f32x4 v0 = *(const f32x4*)src;
        f32x4 v1 = *(const f32x4*)(src + 4);
        *(s16x8*)&Bs[row * 128 + ((gran ^ (row & 7)) * 8)] = cvt8(v0, v1);
    }
    if (t < 64) b3s[t] = b3[t * 64 + i];

    float sreg = 0.f;
    auto stageA = [&](int y, int d) {
        const unsigned short* src = gp + (size_t)y * GELEMS + (size_t)i * GROW;
        #pragma unroll
        for (int p = 0; p < 4; ++p) {
            const int b    = p * 16 + (t >> 4);
            const int gran = t & 15;
            s16x8 v = *(const s16x8*)(src + (size_t)b * (64 * GROW) + gran * 8);
            *(s16x8*)&As[d][b * 128 + ((gran ^ (b & 7)) * 8)] = v;
        }
        if (t < 64) sreg += bf16f(src[(size_t)t * (64 * GROW) + 128]);
    };

    stageA(y0, 0);
    __syncthreads();

    s16x8 bfr[4][4];
    #pragma unroll
    for (int ct = 0; ct < 4; ++ct) {
        const int o = ct * 16 + r;
        #pragma unroll
        for (int ks = 0; ks < 4; ++ks)
            bfr[ct][ks] = *(const s16x8*)&Bs[o * 128 + (((ks * 4 + kg) ^ (o & 7)) * 8)];
    }

    f32x4 acc[4];
    #pragma unroll
    for (int ct = 0; ct < 4; ++ct) { f32x4 z = {0.f,0.f,0.f,0.f}; acc[ct] = z; }

    const int bA = w * 16 + r;
    #pragma unroll
    for (int yy = 0; yy < 4; ++yy) {
        if (yy + 1 < 4) stageA(y0 + yy + 1, (yy + 1) & 1);
        const unsigned short* buf = &As[yy & 1][0];
        s16x8 af[4];
        #pragma unroll
        for (int ks = 0; ks < 4; ++ks)
            af[ks] = *(const s16x8*)&buf[bA * 128 + (((ks * 4 + kg) ^ (bA & 7)) * 8)];
        #pragma unroll
        for (int ct = 0; ct < 4; ++ct)
            #pragma unroll
            for (int ks = 0; ks < 4; ++ks)
                acc[ct] = __builtin_amdgcn_mfma_f32_16x16x32_bf16(af[ks], bfr[ct][ks], acc[ct], 0, 0, 0);
        __syncthreads();
    }

    if (t < 64) sls[t] = sreg;
    __syncthreads();

    float* po = part + (size_t)bid * 4096;
    #pragma unroll
    for (int ct = 0; ct < 4; ++ct) {
        const int o = ct * 16 + r;
        #pragma unroll
        for (int q = 0; q < 4; ++q) {
            const int b = w * 16 + kg * 4 + q;
            po[b * 64 + o] = acc[ct][q] + sls[b] * b3s[o];
        }
    }
}

// ---------------- Kernel 4: out[idx] = bias[idx&63] + sum_p part[p][idx] -----
// 32 blocks x 128 threads (2x CU coverage for the 8 MB partial read).
__global__ __launch_bounds__(128) void k4_final(
        const float* __restrict__ part, const float* __restrict__ bias,
        float* __restrict__ out) {
    const int idx = blockIdx.x * 128 + threadIdx.x;
    float s = bias[idx & 63];
    #pragma unroll 16
    for (int p = 0; p < NPART; ++p)
        s += part[(size_t)p * 4096 + idx];
    out[idx] = s;
}

extern "C" void kernel_launch(void* const* d_in, const int* in_sizes, int n_in,
                              void* d_out, int out_size, void* d_ws, size_t ws_size,
                              hipStream_t stream) {
    (void)in_sizes; (void)n_in; (void)out_size; (void)ws_size;
    const float* x    = (const float*)d_in[0];
    const float* w1   = (const float*)d_in[1];
    const float* b1   = (const float*)d_in[2];
    const float* w2   = (const float*)d_in[3];
    const float* b2   = (const float*)d_in[4];
    const float* w3   = (const float*)d_in[5];
    const float* b3   = (const float*)d_in[6];
    const float* bias = (const float*)d_in[7];
    float* out = (float*)d_out;

    char* ws = (char*)d_ws;
    unsigned short* h2T = (unsigned short*)ws;                          // 2.10 MB
    const size_t H2T_BYTES = (size_t)(LPOS / 64) * CUNITS * 16;
    unsigned short* gp = (unsigned short*)(ws + H2T_BYTES);             // 35.7 MB
    const size_t GP_BYTES = (size_t)KSPLIT * GELEMS * 2;
    float* part = (float*)(ws + H2T_BYTES + GP_BYTES);                  // 8 MB

    k1_siren<<<LPOS / 16, 256, 0, stream>>>(w1, b1, w2, b2, h2T);
    k2_gemm<<<dim3(M_TOT / 128, KSPLIT), 256, 0, stream>>>(x, h2T, gp);
    k3_mm<<<NPART, 256, 0, stream>>>(gp, w3, b3, part);
    k4_final<<<32, 128, 0, stream>>>(part, bias, out);
}

// Round 16
// 66.133 us; speedup vs baseline: 21.7959x; 1.1474x over previous
//
#include <hip/hip_runtime.h>
#include <hip/hip_bf16.h>

#define LPOS 8192
#define HDIM 128
#define M_TOT 4096          // B*Cin
#define GROW  136           // gp row stride (h 0..127, col128 = rowsum, pad to 16B rows)
#define GELEMS (M_TOT * GROW)        // 557056
#define KSPLIT 16
#define CUNITS 1024                  // 16-B units per 64-k chunk
#define BUNITS (4 * CUNITS)          // 4096 units = 65536 B LDS
#define NPART 256

typedef float  f32x4 __attribute__((ext_vector_type(4)));
typedef short  s16x8 __attribute__((ext_vector_type(8)));
typedef unsigned int u32x4 __attribute__((ext_vector_type(4)));

__device__ __forceinline__ unsigned short bf16_rne(float f) {
    unsigned u = __builtin_bit_cast(unsigned, f);
    u += 0x7fffu + ((u >> 16) & 1u);
    return (unsigned short)(u >> 16);
}
__device__ __forceinline__ float bf16f(unsigned short v) {
    return __builtin_bit_cast(float, (unsigned)v << 16);
}

__device__ __forceinline__ s16x8 cvt8(f32x4 a, f32x4 b) {
    s16x8 r;
    r[0] = (short)bf16_rne(a[0]); r[1] = (short)bf16_rne(a[1]);
    r[2] = (short)bf16_rne(a[2]); r[3] = (short)bf16_rne(a[3]);
    r[4] = (short)bf16_rne(b[0]); r[5] = (short)bf16_rne(b[1]);
    r[6] = (short)bf16_rne(b[2]); r[7] = (short)bf16_rne(b[3]);
    return r;
}

__device__ __forceinline__ float sum8(f32x4 a, f32x4 b) {
    return ((a[0] + a[1]) + (a[2] + a[3])) + ((b[0] + b[1]) + (b[2] + b[3]));
}

// ---------------- Kernel 1: SIREN -> h2T (R9 exact) --------------------------
__global__ __launch_bounds__(256) void k1_siren(
        const float* __restrict__ w1, const float* __restrict__ b1,
        const float* __restrict__ w2, const float* __restrict__ b2,
        unsigned short* __restrict__ h2T) {
    __shared__ float w2sT[HDIM * 129];
    __shared__ __align__(16) float h1s[2][HDIM * 8];
    const int tid = threadIdx.x;
    const int s = tid >> 7;
    const int h = tid & 127;

    for (int idx = tid; idx < HDIM * HDIM; idx += 256)
        w2sT[(idx & 127) * 129 + (idx >> 7)] = w2[idx];

    const int l0 = blockIdx.x * 16 + s * 8;
    const float myw1 = w1[h], myb1 = b1[h];
    #pragma unroll
    for (int ls = 0; ls < 8; ++ls) {
        float rel = -1.0f + (2.0f / 8191.0f) * (float)(l0 + ls);
        h1s[s][h * 8 + ls] = __sinf(30.0f * (rel * myw1 + myb1));
    }
    __syncthreads();

    const float bb = b2[h];
    float acc[8];
    #pragma unroll
    for (int ls = 0; ls < 8; ++ls) acc[ls] = bb;

    for (int j = 0; j < HDIM; ++j) {
        float wv = w2sT[j * 129 + h];
        const f32x4* hp = (const f32x4*)&h1s[s][j * 8];
        f32x4 p0 = hp[0], p1 = hp[1];
        acc[0] += wv * p0[0]; acc[1] += wv * p0[1];
        acc[2] += wv * p0[2]; acc[3] += wv * p0[3];
        acc[4] += wv * p1[0]; acc[5] += wv * p1[1];
        acc[6] += wv * p1[2]; acc[7] += wv * p1[3];
    }

    u32x4 ov;
    #pragma unroll
    for (int q = 0; q < 4; ++q) {
        unsigned lo = bf16_rne(__sinf(30.0f * acc[2 * q]));
        unsigned hi = bf16_rne(__sinf(30.0f * acc[2 * q + 1]));
        ov[q] = lo | (hi << 16);
    }
    const size_t c = (size_t)(l0 >> 6);
    const int k8 = (l0 >> 3) & 7;
    *(u32x4*)(h2T + (c * CUNITS + (size_t)k8 * 128 + h) * 8) = ov;
}

// ---------------- Kernel 2: partial GEMM, 2 chunk-groups per block -----------
// R9 loop shape run twice (g=0,1), acc/rowsum accumulate across both groups,
// ONE store. Grid (32, 16) = 512 blocks; gp halves to 17.8 MB.
__global__ __launch_bounds__(256, 2) void k2_gemm(
        const float* __restrict__ x, const unsigned short* __restrict__ h2T,
        unsigned short* __restrict__ gp) {
    __shared__ unsigned short lds[BUNITS * 8];     // 65536 B

    const int lane = threadIdx.x & 63;
    const int wv   = threadIdx.x >> 6;
    const int r    = lane & 15;
    const int kg   = lane >> 4;
    const int m0   = blockIdx.x * 128;
    const int y8   = blockIdx.y;                   // 0..15, covers 512 k
    const int kc   = y8 * 512;

    const float* xpa = x + (size_t)(m0 + wv * 32 + r) * LPOS + kc + kg * 8;
    const float* xpb = xpa + 16 * LPOS;

    f32x4 xr[2][2][4];

#define LOADX(SL, IT) do { \
        xr[SL][0][0] = *(const f32x4*)(xpa + (IT) * 64);      \
        xr[SL][0][1] = *(const f32x4*)(xpa + (IT) * 64 + 4);  \
        xr[SL][0][2] = *(const f32x4*)(xpa + (IT) * 64 + 32); \
        xr[SL][0][3] = *(const f32x4*)(xpa + (IT) * 64 + 36); \
        xr[SL][1][0] = *(const f32x4*)(xpb + (IT) * 64);      \
        xr[SL][1][1] = *(const f32x4*)(xpb + (IT) * 64 + 4);  \
        xr[SL][1][2] = *(const f32x4*)(xpb + (IT) * 64 + 32); \
        xr[SL][1][3] = *(const f32x4*)(xpb + (IT) * 64 + 36); \
    } while (0)

    f32x4 acc[2][8];
    #pragma unroll
    for (int s = 0; s < 2; ++s)
        #pragma unroll
        for (int t = 0; t < 8; ++t) { f32x4 z = {0.f,0.f,0.f,0.f}; acc[s][t] = z; }
    float sacc0 = 0.f, sacc1 = 0.f;

    #pragma unroll 1
    for (int g = 0; g < 2; ++g) {
        const int base = g * 4;                    // 64-k iteration base
        {   // stage B for chunk-group g (4 chunks = 64 KB)
            const unsigned short* src = h2T + (size_t)(y8 * 2 + g) * (BUNITS * 8);
            #pragma unroll
            for (int j = 0; j < 16; ++j) {
                const int U = j * 256 + threadIdx.x;
                __builtin_amdgcn_global_load_lds(
                    (const unsigned int*)(src + (size_t)U * 8),
                    (unsigned int*)&lds[U * 8], 16, 0, 0);
            }
        }
        LOADX(0, base); LOADX(1, base + 1);
        __syncthreads();                           // B staged + x0/x1 arrived

        #pragma unroll
        for (int it = 0; it < 4; ++it) {
            const int sl = it & 1;
            s16x8 a0lo = cvt8(xr[sl][0][0], xr[sl][0][1]);
            s16x8 a0hi = cvt8(xr[sl][0][2], xr[sl][0][3]);
            s16x8 a1lo = cvt8(xr[sl][1][0], xr[sl][1][1]);
            s16x8 a1hi = cvt8(xr[sl][1][2], xr[sl][1][3]);
            sacc0 += sum8(xr[sl][0][0], xr[sl][0][1]) + sum8(xr[sl][0][2], xr[sl][0][3]);
            sacc1 += sum8(xr[sl][1][0], xr[sl][1][1]) + sum8(xr[sl][1][2], xr[sl][1][3]);
            if (it + 2 < 4) LOADX(sl, base + it + 2);

            #pragma unroll
            for (int t = 0; t < 8; ++t) {
                s16x8 blo = *(const s16x8*)&lds[((size_t)it * CUNITS + kg * 128 + t * 16 + r) * 8];
                s16x8 bhi = *(const s16x8*)&lds[((size_t)it * CUNITS + (kg + 4) * 128 + t * 16 + r) * 8];
                acc[0][t] = __builtin_amdgcn_mfma_f32_16x16x32_bf16(a0lo, blo, acc[0][t], 0, 0, 0);
                acc[0][t] = __builtin_amdgcn_mfma_f32_16x16x32_bf16(a0hi, bhi, acc[0][t], 0, 0, 0);
                acc[1][t] = __builtin_amdgcn_mfma_f32_16x16x32_bf16(a1lo, blo, acc[1][t], 0, 0, 0);
                acc[1][t] = __builtin_amdgcn_mfma_f32_16x16x32_bf16(a1hi, bhi, acc[1][t], 0, 0, 0);
            }
        }
        __syncthreads();                           // all reads of B(g) done before restage
    }
#undef LOADX

    unsigned short* gpy = gp + (size_t)y8 * GELEMS;
    #pragma unroll
    for (int s = 0; s < 2; ++s) {
        #pragma unroll
        for (int t = 0; t < 8; ++t) {
            const int col = t * 16 + r;
            #pragma unroll
            for (int q = 0; q < 4; ++q) {
                const int row = m0 + wv * 32 + s * 16 + kg * 4 + q;
                gpy[(size_t)row * GROW + col] = bf16_rne(acc[s][t][q]);
            }
        }
    }
    sacc0 += __shfl_xor(sacc0, 16); sacc0 += __shfl_xor(sacc0, 32);
    sacc1 += __shfl_xor(sacc1, 16); sacc1 += __shfl_xor(sacc1, 32);
    if (kg == 0) {
        gpy[(size_t)(m0 + wv * 32 + r) * GROW + 128]      = bf16_rne(sacc0);
        gpy[(size_t)(m0 + wv * 32 + 16 + r) * GROW + 128] = bf16_rne(sacc1);
    }
}

// ---------------- Kernel 3: per-i contraction (R9 block layout, 4-y loop) ----
// bid = i*4 + yg (256 blocks); y0 = yg*4; gp now has 16 y-slices.
__global__ __launch_bounds__(256, 3) void k3_mm(
        const unsigned short* __restrict__ gp, const float* __restrict__ w3,
        const float* __restrict__ b3, float* __restrict__ part) {
    __shared__ unsigned short As[2][64 * 128];   // 2 x 16 KB
    __shared__ unsigned short Bs[64 * 128];      // 16 KB
    __shared__ float b3s[64];
    __shared__ float sls[64];

    const int bid = blockIdx.x;
    const int i   = bid >> 2;
    const int y0  = (bid & 3) * 4;
    const int t    = threadIdx.x;
    const int lane = t & 63;
    const int w    = t >> 6;
    const int r    = lane & 15;
    const int kg   = lane >> 4;

    #pragma unroll
    for (int p = 0; p < 4; ++p) {
        const int row  = p * 16 + (t >> 4);
        const int gran = t & 15;
        const float* src = w3 + (size_t)(row * 64 + i) * HDIM + gran * 8;
        f32x4 v0 = *(const f32x4*)src;
        f32x4 v1 = *(const f32x4*)(src + 4);
        *(s16x8*)&Bs[row * 128 + ((gran ^ (row & 7)) * 8)] = cvt8(v0, v1);
    }
    if (t < 64) b3s[t] = b3[t * 64 + i];

    float sreg = 0.f;
    auto stageA = [&](int y, int d) {
        const unsigned short* src = gp + (size_t)y * GELEMS + (size_t)i * GROW;
        #pragma unroll
        for (int p = 0; p < 4; ++p) {
            const int b    = p * 16 + (t >> 4);
            const int gran = t & 15;
            s16x8 v = *(const s16x8*)(src + (size_t)b * (64 * GROW) + gran * 8);
            *(s16x8*)&As[d][b * 128 + ((gran ^ (b & 7)) * 8)] = v;
        }
        if (t < 64) sreg += bf16f(src[(size_t)t * (64 * GROW) + 128]);
    };

    stageA(y0, 0);
    __syncthreads();

    s16x8 bfr[4][4];
    #pragma unroll
    for (int ct = 0; ct < 4; ++ct) {
        const int o = ct * 16 + r;
        #pragma unroll
        for (int ks = 0; ks < 4; ++ks)
            bfr[ct][ks] = *(const s16x8*)&Bs[o * 128 + (((ks * 4 + kg) ^ (o & 7)) * 8)];
    }

    f32x4 acc[4];
    #pragma unroll
    for (int ct = 0; ct < 4; ++ct) { f32x4 z = {0.f,0.f,0.f,0.f}; acc[ct] = z; }

    const int bA = w * 16 + r;
    #pragma unroll
    for (int yy = 0; yy < 4; ++yy) {
        if (yy + 1 < 4) stageA(y0 + yy + 1, (yy + 1) & 1);
        const unsigned short* buf = &As[yy & 1][0];
        s16x8 af[4];
        #pragma unroll
        for (int ks = 0; ks < 4; ++ks)
            af[ks] = *(const s16x8*)&buf[bA * 128 + (((ks * 4 + kg) ^ (bA & 7)) * 8)];
        #pragma unroll
        for (int ct = 0; ct < 4; ++ct)
            #pragma unroll
            for (int ks = 0; ks < 4; ++ks)
                acc[ct] = __builtin_amdgcn_mfma_f32_16x16x32_bf16(af[ks], bfr[ct][ks], acc[ct], 0, 0, 0);
        __syncthreads();
    }

    if (t < 64) sls[t] = sreg;
    __syncthreads();

    float* po = part + (size_t)bid * 4096;
    #pragma unroll
    for (int ct = 0; ct < 4; ++ct) {
        const int o = ct * 16 + r;
        #pragma unroll
        for (int q = 0; q < 4; ++q) {
            const int b = w * 16 + kg * 4 + q;
            po[b * 64 + o] = acc[ct][q] + sls[b] * b3s[o];
        }
    }
}

// ---------------- Kernel 4: out[idx] = bias[idx&63] + sum_p part[p][idx] -----
__global__ __launch_bounds__(256) void k4_final(
        const float* __restrict__ part, const float* __restrict__ bias,
        float* __restrict__ out) {
    const int idx = blockIdx.x * 256 + threadIdx.x;
    float s = bias[idx & 63];
    #pragma unroll 8
    for (int p = 0; p < NPART; ++p)
        s += part[(size_t)p * 4096 + idx];
    out[idx] = s;
}

extern "C" void kernel_launch(void* const* d_in, const int* in_sizes, int n_in,
                              void* d_out, int out_size, void* d_ws, size_t ws_size,
                              hipStream_t stream) {
    (void)in_sizes; (void)n_in; (void)out_size; (void)ws_size;
    const float* x    = (const float*)d_in[0];
    const float* w1   = (const float*)d_in[1];
    const float* b1   = (const float*)d_in[2];
    const float* w2   = (const float*)d_in[3];
    const float* b2   = (const float*)d_in[4];
    const float* w3   = (const float*)d_in[5];
    const float* b3   = (const float*)d_in[6];
    const float* bias = (const float*)d_in[7];
    float* out = (float*)d_out;

    char* ws = (char*)d_ws;
    unsigned short* h2T = (unsigned short*)ws;                          // 2.10 MB
    const size_t H2T_BYTES = (size_t)(LPOS / 64) * CUNITS * 16;
    unsigned short* gp = (unsigned short*)(ws + H2T_BYTES);             // 17.8 MB
    const size_t GP_BYTES = (size_t)KSPLIT * GELEMS * 2;
    float* part = (float*)(ws + H2T_BYTES + GP_BYTES);                  // 4 MB

    k1_siren<<<LPOS / 16, 256, 0, stream>>>(w1, b1, w2, b2, h2T);
    k2_gemm<<<dim3(M_TOT / 128, KSPLIT), 256, 0, stream>>>(x, h2T, gp);
    k3_mm<<<NPART, 256, 0, stream>>>(gp, w3, b3, part);
    k4_final<<<16, 256, 0, stream>>>(part, bias, out);
}